// Round 1
// baseline (5827.981 us; speedup 1.0000x reference)
//
#include <hip/hip_runtime.h>
#include <math.h>

// ---------------- constants ----------------
// IMG=512 P=16 CIN=3 COUT=3 E=768 NHEADS=12 L=8 NPH=32 N=1024 HD=64 INTER=128
// rows M = B*N = 2048 for all token GEMMs.

// ---------------- PE table ----------------
__global__ __launch_bounds__(256) void pe_kernel(float* __restrict__ pe) {
    int idx = blockIdx.x * 256 + threadIdx.x;      // < 1024*768
    int n = idx / 768, d = idx - n * 768;
    float v = 0.0f;
    if (d < 384) {
        int pos = (d < 192) ? (n >> 5) : (n & 31); // row pos for first quarter-pair, col pos for second
        int dd  = (d < 192) ? d : d - 192;
        int j2  = dd & ~1;                          // arange(0,192,2) value
        float dv  = expf((float)j2 * (-9.210340371976184f / 192.0f)); // -ln(1e4)/dq
        float ang = (float)pos * dv;
        v = (dd & 1) ? cosf(ang) : sinf(ang);
    }
    pe[idx] = v;
}

// ---------------- patch gather: x(2,3,512,512) -> xp(2048,768) ----------------
__global__ __launch_bounds__(256) void gather_kernel(const float* __restrict__ x,
                                                     float* __restrict__ xp) {
    int idx = blockIdx.x * 256 + threadIdx.x;      // < 2048*768
    int m = idx / 768, col = idx - m * 768;
    int b = m >> 10, n = m & 1023;
    int ci = col >> 8, rem = col & 255;
    int pr = rem >> 4, pc = rem & 15;
    int hh = ((n >> 5) << 4) + pr;
    int ww = ((n & 31) << 4) + pc;
    xp[idx] = x[(((size_t)(b * 3 + ci) * 512) + hh) * 512 + ww];
}

// ---------------- LayerNorm over 768 cols ----------------
__global__ __launch_bounds__(256) void ln_kernel(const float* __restrict__ x,
                                                 const float* __restrict__ g,
                                                 const float* __restrict__ b,
                                                 float* __restrict__ y) {
    int row = blockIdx.x, tid = threadIdx.x;
    const float* xr = x + (size_t)row * 768;
    float v0 = xr[tid], v1 = xr[tid + 256], v2 = xr[tid + 512];
    __shared__ float red[256];
    red[tid] = v0 + v1 + v2;
    __syncthreads();
    for (int off = 128; off > 0; off >>= 1) {
        if (tid < off) red[tid] += red[tid + off];
        __syncthreads();
    }
    float mean = red[0] * (1.0f / 768.0f);
    __syncthreads();
    float d0 = v0 - mean, d1 = v1 - mean, d2 = v2 - mean;
    red[tid] = d0 * d0 + d1 * d1 + d2 * d2;
    __syncthreads();
    for (int off = 128; off > 0; off >>= 1) {
        if (tid < off) red[tid] += red[tid + off];
        __syncthreads();
    }
    float rstd = rsqrtf(red[0] * (1.0f / 768.0f) + 1e-5f);
    float* yr = y + (size_t)row * 768;
    yr[tid]       = d0 * rstd * g[tid]       + b[tid];
    yr[tid + 256] = d1 * rstd * g[tid + 256] + b[tid + 256];
    yr[tid + 512] = d2 * rstd * g[tid + 512] + b[tid + 512];
}

// ---------------- generic GEMM: C = A(MxK) * B(NxK)^T, epilogue by MODE ----------------
// MODE 0: C = acc                       (qkv)
// MODE 1: C = acc + bias[n] + pe[m%1024][n]            (embed)
// MODE 2: C = res[m][n] + add2[m][n] + acc + bias[n]   (proj + double residual)
// MODE 3: C = gelu_exact(acc + bias[n])                (mlp1)
// MODE 4: C = res[m][n] + acc + bias[n]                (mlp2)
// MODE 5: C = relu(acc + bias[n])                      (op1)
// MODE 6: C = acc + bias[n]                            (op2)
template <int MODE>
__global__ __launch_bounds__(256) void gemm_nt(const float* __restrict__ A,
                                               const float* __restrict__ B,
                                               const float* __restrict__ bias,
                                               const float* __restrict__ res,
                                               const float* __restrict__ add2,
                                               float* __restrict__ C,
                                               int M, int N, int K) {
    __shared__ float As[128][20];
    __shared__ float Bs[128][20];
    int tid = threadIdx.x;
    int tx = tid & 15, ty = tid >> 4;
    int m0 = blockIdx.y * 128, n0 = blockIdx.x * 128;
    int lr = tid >> 2;            // 0..63
    int lc = (tid & 3) * 4;       // 0,4,8,12
    const float* Ab = A + (size_t)m0 * K;
    const float* Bb = B + (size_t)n0 * K;
    float acc[8][8] = {};
    for (int kt = 0; kt < K; kt += 16) {
        float4 a0 = *(const float4*)(Ab + (size_t)lr * K + kt + lc);
        float4 a1 = *(const float4*)(Ab + (size_t)(lr + 64) * K + kt + lc);
        float4 b0 = *(const float4*)(Bb + (size_t)lr * K + kt + lc);
        float4 b1 = *(const float4*)(Bb + (size_t)(lr + 64) * K + kt + lc);
        __syncthreads();
        *(float4*)&As[lr][lc] = a0;
        *(float4*)&As[lr + 64][lc] = a1;
        *(float4*)&Bs[lr][lc] = b0;
        *(float4*)&Bs[lr + 64][lc] = b1;
        __syncthreads();
#pragma unroll
        for (int kk = 0; kk < 16; kk++) {
            float a[8], bv[8];
#pragma unroll
            for (int i = 0; i < 8; i++) a[i] = As[i * 16 + ty][kk];
#pragma unroll
            for (int j = 0; j < 8; j++) bv[j] = Bs[j * 16 + tx][kk];
#pragma unroll
            for (int i = 0; i < 8; i++)
#pragma unroll
                for (int j = 0; j < 8; j++) acc[i][j] += a[i] * bv[j];
        }
    }
#pragma unroll
    for (int i = 0; i < 8; i++) {
        int m = m0 + i * 16 + ty;
#pragma unroll
        for (int j = 0; j < 8; j++) {
            int n = n0 + j * 16 + tx;
            float v = acc[i][j];
            if (MODE == 1) v += bias[n] + add2[(size_t)(m & 1023) * N + n];
            else if (MODE == 2) v = res[(size_t)m * N + n] + add2[(size_t)m * N + n] + v + bias[n];
            else if (MODE == 3) { v += bias[n]; v = 0.5f * v * (1.0f + erff(v * 0.70710678118654752f)); }
            else if (MODE == 4) v = res[(size_t)m * N + n] + v + bias[n];
            else if (MODE == 5) { v += bias[n]; v = v > 0.0f ? v : 0.0f; }
            else if (MODE == 6) v += bias[n];
            C[(size_t)m * N + n] = v;
        }
    }
}

// ---------------- flash attention: per (b,h) x 64-query tile ----------------
__global__ __launch_bounds__(256) void attn_kernel(const float* __restrict__ qkv,
                                                   const float* __restrict__ bias,
                                                   float* __restrict__ o) {
    __shared__ float Qs[64][68];
    __shared__ float Ks[64][68];   // reused as P after score phase
    __shared__ float Vs[64][68];
    int tid = threadIdx.x;
    int tx = tid & 15, ty = tid >> 4;
    int n0 = blockIdx.x * 64;
    int bh = blockIdx.y;
    int b = bh / 12, h = bh % 12;
    const size_t ROWW = 2304;
    const float* qbase = qkv + (size_t)(b * 1024) * ROWW + h * 64;
    const float* kbase = qbase + 768;
    const float* vbase = qbase + 1536;
    int lr = tid >> 4;            // 0..15
    int lc4 = (tid & 15) * 4;     // 0..60
#pragma unroll
    for (int rr = 0; rr < 4; rr++) {
        int r = lr + rr * 16;
        *(float4*)&Qs[r][lc4] = *(const float4*)(qbase + (size_t)(n0 + r) * ROWW + lc4);
    }
    float m_i[4], l_i[4], oacc[4][4] = {};
#pragma unroll
    for (int i = 0; i < 4; i++) { m_i[i] = -1e30f; l_i[i] = 0.0f; }
    __syncthreads();
    for (int t0 = 0; t0 < 1024; t0 += 64) {
        __syncthreads();   // previous iteration's P@V readers done with Ks/Vs
#pragma unroll
        for (int rr = 0; rr < 4; rr++) {
            int r = lr + rr * 16;
            *(float4*)&Ks[r][lc4] = *(const float4*)(kbase + (size_t)(t0 + r) * ROWW + lc4);
            *(float4*)&Vs[r][lc4] = *(const float4*)(vbase + (size_t)(t0 + r) * ROWW + lc4);
        }
        __syncthreads();
        float s[4][4] = {};
#pragma unroll 4
        for (int d = 0; d < 64; d++) {
            float a[4], kv[4];
#pragma unroll
            for (int i = 0; i < 4; i++) a[i] = Qs[i * 16 + ty][d];
#pragma unroll
            for (int j = 0; j < 4; j++) kv[j] = Ks[j * 16 + tx][d];
#pragma unroll
            for (int i = 0; i < 4; i++)
#pragma unroll
                for (int j = 0; j < 4; j++) s[i][j] += a[i] * kv[j];
        }
        float scl[4];
#pragma unroll
        for (int i = 0; i < 4; i++) {
            int row = n0 + i * 16 + ty;
            float pm = -1e30f;
#pragma unroll
            for (int j = 0; j < 4; j++) {
                s[i][j] = s[i][j] * 0.125f + bias[(size_t)row * 1024 + t0 + j * 16 + tx];
                pm = fmaxf(pm, s[i][j]);
            }
#pragma unroll
            for (int off = 1; off < 16; off <<= 1) pm = fmaxf(pm, __shfl_xor(pm, off, 64));
            float mnew = fmaxf(m_i[i], pm);
            scl[i] = __expf(m_i[i] - mnew);
            float rs = 0.0f;
#pragma unroll
            for (int j = 0; j < 4; j++) {
                float p = __expf(s[i][j] - mnew);
                s[i][j] = p;
                rs += p;
            }
#pragma unroll
            for (int off = 1; off < 16; off <<= 1) rs += __shfl_xor(rs, off, 64);
            l_i[i] = l_i[i] * scl[i] + rs;
            m_i[i] = mnew;
        }
        __syncthreads();   // all lanes done reading Ks as K
#pragma unroll
        for (int i = 0; i < 4; i++)
#pragma unroll
            for (int j = 0; j < 4; j++) Ks[i * 16 + ty][j * 16 + tx] = s[i][j];
        __syncthreads();
#pragma unroll
        for (int i = 0; i < 4; i++)
#pragma unroll
            for (int j = 0; j < 4; j++) oacc[i][j] *= scl[i];
#pragma unroll 4
        for (int kk = 0; kk < 64; kk++) {
            float p[4], vv[4];
#pragma unroll
            for (int i = 0; i < 4; i++) p[i] = Ks[i * 16 + ty][kk];
#pragma unroll
            for (int j = 0; j < 4; j++) vv[j] = Vs[kk][j * 16 + tx];
#pragma unroll
            for (int i = 0; i < 4; i++)
#pragma unroll
                for (int j = 0; j < 4; j++) oacc[i][j] += p[i] * vv[j];
        }
    }
#pragma unroll
    for (int i = 0; i < 4; i++) {
        int r = n0 + i * 16 + ty;
        float invl = 1.0f / l_i[i];
#pragma unroll
        for (int j = 0; j < 4; j++)
            o[(size_t)(b * 1024 + r) * 768 + h * 64 + j * 16 + tx] = oacc[i][j] * invl;
    }
}

// ---------------- fold + attention gate -> out(2,3,512,512) ----------------
__global__ __launch_bounds__(256) void fold_gate(const float* __restrict__ hbuf,
                                                 const float* __restrict__ xin,
                                                 const float* __restrict__ wg,
                                                 const float* __restrict__ bngw,
                                                 const float* __restrict__ bngb,
                                                 const float* __restrict__ wx,
                                                 const float* __restrict__ bnxw,
                                                 const float* __restrict__ bnxb,
                                                 const float* __restrict__ psiw,
                                                 const float* __restrict__ psib,
                                                 float* __restrict__ out) {
    int idx = blockIdx.x * 256 + threadIdx.x;      // < 2*512*512
    int b = idx >> 18;
    int rem = idx & 262143;
    int hh = rem >> 9, ww = rem & 511;
    int n = ((hh >> 4) << 5) + (ww >> 4);
    int pr = hh & 15, pc = ww & 15;
    const float* hrow = hbuf + (size_t)(b * 1024 + n) * 768 + pr * 16 + pc;
    float g0 = hrow[0], g1 = hrow[256], g2 = hrow[512];
    size_t xoff = ((size_t)(b * 3) * 512 + hh) * 512 + ww;
    float x0 = xin[xoff], x1 = xin[xoff + 262144], x2 = xin[xoff + 524288];
    float inv = rsqrtf(1.0f + 1e-5f);
    float gg = (g0 * wg[0] + g1 * wg[1] + g2 * wg[2]) * inv * bngw[0] + bngb[0];
    float xx = (x0 * wx[0] + x1 * wx[1] + x2 * wx[2]) * inv * bnxw[0] + bnxb[0];
    float z = gg + xx;
    z = z > 0.0f ? z : 0.0f;
    float psi = 1.0f / (1.0f + expf(-(z * psiw[0] + psib[0])));
    out[xoff]          = g0 * x0 * psi;
    out[xoff + 262144] = g1 * x1 * psi;
    out[xoff + 524288] = g2 * x2 * psi;
}

// ---------------- launch ----------------
extern "C" void kernel_launch(void* const* d_in, const int* in_sizes, int n_in,
                              void* d_out, int out_size, void* d_ws, size_t ws_size,
                              hipStream_t stream) {
    (void)in_sizes; (void)n_in; (void)out_size; (void)ws_size;
    const float* x       = (const float*)d_in[0];
    const float* conv_w  = (const float*)d_in[1];
    const float* conv_b  = (const float*)d_in[2];
    const float* ln1_g   = (const float*)d_in[3];
    const float* ln1_b   = (const float*)d_in[4];
    const float* qkv_w   = (const float*)d_in[5];
    const float* proj_w  = (const float*)d_in[6];
    const float* proj_b  = (const float*)d_in[7];
    const float* attn_bs = (const float*)d_in[8];
    const float* ln2_g   = (const float*)d_in[9];
    const float* ln2_b   = (const float*)d_in[10];
    const float* mlp_w1  = (const float*)d_in[11];
    const float* mlp_b1  = (const float*)d_in[12];
    const float* mlp_w2  = (const float*)d_in[13];
    const float* mlp_b2  = (const float*)d_in[14];
    const float* op_w1   = (const float*)d_in[15];
    const float* op_b1   = (const float*)d_in[16];
    const float* op_w2   = (const float*)d_in[17];
    const float* op_b2   = (const float*)d_in[18];
    const float* ag_wg   = (const float*)d_in[19];
    const float* ag_bngw = (const float*)d_in[20];
    const float* ag_bngb = (const float*)d_in[21];
    const float* ag_wx   = (const float*)d_in[22];
    const float* ag_bnxw = (const float*)d_in[23];
    const float* ag_bnxb = (const float*)d_in[24];
    const float* ag_psiw = (const float*)d_in[25];
    const float* ag_psib = (const float*)d_in[26];
    float* out = (float*)d_out;

    float* ws   = (float*)d_ws;
    float* pe   = ws;                 //  786432
    float* xp   = ws + 786432;        // 1572864
    float* t    = ws + 2359296;       // 1572864
    float* y    = ws + 3932160;       // 1572864
    float* qkv  = ws + 5505024;       // 4718592 (also reused below)
    float* att  = ws + 10223616;      // 1572864  -> total 11796480 floats = 47.2 MB
    float* mlph = qkv;                // 3145728 fits in qkv region
    float* oph1 = qkv;                //  262144
    float* oph2 = qkv + 262144;       // 1572864

    pe_kernel<<<3072, 256, 0, stream>>>(pe);
    gather_kernel<<<6144, 256, 0, stream>>>(x, xp);
    gemm_nt<1><<<dim3(6, 16), 256, 0, stream>>>(xp, conv_w, conv_b, nullptr, pe, t, 2048, 768, 768);

    for (int l = 0; l < 8; ++l) {
        ln_kernel<<<2048, 256, 0, stream>>>(t, ln1_g + l * 768, ln1_b + l * 768, y);
        gemm_nt<0><<<dim3(18, 16), 256, 0, stream>>>(y, qkv_w + (size_t)l * 2304 * 768,
                                                     nullptr, nullptr, nullptr, qkv, 2048, 2304, 768);
        attn_kernel<<<dim3(16, 24), 256, 0, stream>>>(qkv, attn_bs + (size_t)l * 1048576, att);
        gemm_nt<2><<<dim3(6, 16), 256, 0, stream>>>(att, proj_w + (size_t)l * 589824,
                                                    proj_b + l * 768, t, y, t, 2048, 768, 768);
        ln_kernel<<<2048, 256, 0, stream>>>(t, ln2_g + l * 768, ln2_b + l * 768, y);
        gemm_nt<3><<<dim3(12, 16), 256, 0, stream>>>(y, mlp_w1 + (size_t)l * 1179648,
                                                     mlp_b1 + l * 1536, nullptr, nullptr, mlph, 2048, 1536, 768);
        gemm_nt<4><<<dim3(6, 16), 256, 0, stream>>>(mlph, mlp_w2 + (size_t)l * 1179648,
                                                    mlp_b2 + l * 768, t, nullptr, t, 2048, 768, 1536);
    }

    gemm_nt<5><<<dim3(1, 16), 256, 0, stream>>>(t, op_w1, op_b1, nullptr, nullptr, oph1, 2048, 128, 768);
    gemm_nt<6><<<dim3(6, 16), 256, 0, stream>>>(oph1, op_w2, op_b2, nullptr, nullptr, oph2, 2048, 768, 128);
    fold_gate<<<2048, 256, 0, stream>>>(oph2, x, ag_wg, ag_bngw, ag_bngb,
                                        ag_wx, ag_bnxw, ag_bnxb, ag_psiw, ag_psib, out);
}

// Round 2
// 2556.314 us; speedup vs baseline: 2.2798x; 2.2798x over previous
//
#include <hip/hip_runtime.h>
#include <math.h>

typedef unsigned short u16;
typedef unsigned int u32;
typedef __attribute__((ext_vector_type(8))) short bf16x8;
typedef __attribute__((ext_vector_type(16))) float f32x16;

// ---------------- helpers ----------------
__device__ __forceinline__ float bf2f(u16 h) { return __uint_as_float(((u32)h) << 16); }

__device__ __forceinline__ void split2(float v, u16& h, u16& l) {
    u32 u = __float_as_uint(v);
    u32 hr = (u + 0x7FFFu + ((u >> 16) & 1u)) & 0xFFFF0000u;
    h = (u16)(hr >> 16);
    float lf = v - __uint_as_float(hr);
    u32 ul = __float_as_uint(lf);
    l = (u16)((ul + 0x7FFFu + ((ul >> 16) & 1u)) >> 16);
}

// ---------------- PE table ----------------
__global__ __launch_bounds__(256) void pe_kernel(float* __restrict__ pe) {
    int idx = blockIdx.x * 256 + threadIdx.x;      // < 1024*768
    int n = idx / 768, d = idx - n * 768;
    float v = 0.0f;
    if (d < 384) {
        int pos = (d < 192) ? (n >> 5) : (n & 31);
        int dd  = (d < 192) ? d : d - 192;
        int j2  = dd & ~1;
        float dv  = expf((float)j2 * (-9.210340371976184f / 192.0f));
        float ang = (float)pos * dv;
        v = (dd & 1) ? cosf(ang) : sinf(ang);
    }
    pe[idx] = v;
}

// ---------------- patch gather: x(2,3,512,512) -> xp hi/lo (2048,768) bf16 ----------------
__global__ __launch_bounds__(256) void gather_kernel(const float* __restrict__ x,
                                                     u16* __restrict__ xph,
                                                     u16* __restrict__ xpl) {
    int idx = blockIdx.x * 256 + threadIdx.x;      // < 2048*768
    int m = idx / 768, col = idx - m * 768;
    int b = m >> 10, n = m & 1023;
    int ci = col >> 8, rem = col & 255;
    int pr = rem >> 4, pc = rem & 15;
    int hh = ((n >> 5) << 4) + pr;
    int ww = ((n & 31) << 4) + pc;
    float v = x[(((size_t)(b * 3 + ci) * 512) + hh) * 512 + ww];
    split2(v, xph[idx], xpl[idx]);
}

// ---------------- generic fp32 -> hi/lo bf16 split (float4-granular) ----------------
__global__ __launch_bounds__(256) void fsplit(const float* __restrict__ in,
                                              u16* __restrict__ h, u16* __restrict__ l, int n4) {
    int i = blockIdx.x * 256 + threadIdx.x;
    if (i >= n4) return;
    float4 v = ((const float4*)in)[i];
    int o = i * 4;
    split2(v.x, h[o], l[o]);
    split2(v.y, h[o + 1], l[o + 1]);
    split2(v.z, h[o + 2], l[o + 2]);
    split2(v.w, h[o + 3], l[o + 3]);
}

// ---------------- per-layer weight split: qkv|proj|mlp1|mlp2 -> w_hi/w_lo ----------------
// ushort offsets: QKV 0, PROJ 1769472, MLP1 2359296, MLP2 3538944, total 4718592
__global__ __launch_bounds__(256) void wsplit_layer(const float* __restrict__ qkvw,
                                                    const float* __restrict__ projw,
                                                    const float* __restrict__ w1,
                                                    const float* __restrict__ w2,
                                                    u16* __restrict__ wh, u16* __restrict__ wl) {
    int i4 = blockIdx.x * 256 + threadIdx.x;       // < 1179648
    if (i4 >= 1179648) return;
    size_t idx = (size_t)i4 * 4;
    const float* src; size_t off;
    if (idx < 1769472)      { src = qkvw;  off = idx; }
    else if (idx < 2359296) { src = projw; off = idx - 1769472; }
    else if (idx < 3538944) { src = w1;    off = idx - 2359296; }
    else                    { src = w2;    off = idx - 3538944; }
    float4 v = *(const float4*)(src + off);
    split2(v.x, wh[idx], wl[idx]);
    split2(v.y, wh[idx + 1], wl[idx + 1]);
    split2(v.z, wh[idx + 2], wl[idx + 2]);
    split2(v.w, wh[idx + 3], wl[idx + 3]);
}

// ---------------- LayerNorm over 768 cols -> hi/lo bf16 ----------------
__global__ __launch_bounds__(256) void ln_kernel(const float* __restrict__ x,
                                                 const float* __restrict__ g,
                                                 const float* __restrict__ b,
                                                 u16* __restrict__ yh, u16* __restrict__ yl) {
    int row = blockIdx.x, tid = threadIdx.x;
    const float* xr = x + (size_t)row * 768;
    float v0 = xr[tid], v1 = xr[tid + 256], v2 = xr[tid + 512];
    __shared__ float red[256];
    red[tid] = v0 + v1 + v2;
    __syncthreads();
    for (int off = 128; off > 0; off >>= 1) {
        if (tid < off) red[tid] += red[tid + off];
        __syncthreads();
    }
    float mean = red[0] * (1.0f / 768.0f);
    __syncthreads();
    float d0 = v0 - mean, d1 = v1 - mean, d2 = v2 - mean;
    red[tid] = d0 * d0 + d1 * d1 + d2 * d2;
    __syncthreads();
    for (int off = 128; off > 0; off >>= 1) {
        if (tid < off) red[tid] += red[tid + off];
        __syncthreads();
    }
    float rstd = rsqrtf(red[0] * (1.0f / 768.0f) + 1e-5f);
    size_t o = (size_t)row * 768;
    split2(d0 * rstd * g[tid]       + b[tid],       yh[o + tid],       yl[o + tid]);
    split2(d1 * rstd * g[tid + 256] + b[tid + 256], yh[o + tid + 256], yl[o + tid + 256]);
    split2(d2 * rstd * g[tid + 512] + b[tid + 512], yh[o + tid + 512], yl[o + tid + 512]);
}

// ---------------- split-bf16 MFMA GEMM: C = A(MxK) * B(NxK)^T ----------------
// A,B given as hi/lo bf16 pairs. 128x128 tile, BK=32, 4 waves of 64x64,
// v_mfma_f32_32x32x16_bf16, 3-term split (hh+hl+lh).
// LDS: [2 bufs][4 tiles: Ah,Al,Bh,Bl][128 rows][32 bf16], XOR(chunk,row&3) swizzle.
// MODE 0: C=acc (qkv)          MODE 1: C=acc+bias+pe[(m&1023)][n] (embed)
// MODE 2: C=res+ (auxh+auxl) + acc + bias (proj, double residual)
// MODE 3: hi/lo out = gelu(acc+bias) (mlp1)
// MODE 4: C=res+acc+bias (mlp2)
// MODE 5: hi/lo out = relu(acc+bias) (op1)
// MODE 6: C=acc+bias (op2)
template <int MODE>
__global__ __launch_bounds__(256, 2) void gemm_sp(const u16* __restrict__ Ah, const u16* __restrict__ Al,
                                                  const u16* __restrict__ Bh, const u16* __restrict__ Bl,
                                                  const float* __restrict__ bias,
                                                  const float* __restrict__ res,
                                                  const float* __restrict__ auxf,
                                                  const u16* __restrict__ auxh, const u16* __restrict__ auxl,
                                                  float* __restrict__ C, u16* __restrict__ Ch, u16* __restrict__ Cl,
                                                  int M, int N, int K) {
    __shared__ u16 smem[2][4][4096];   // 64 KB
    int tid = threadIdx.x;
    int wid = tid >> 6, lane = tid & 63;
    int wm = wid >> 1, wn = wid & 1;
    int m0 = blockIdx.y * 128, n0 = blockIdx.x * 128;

    // staging geometry (per wave): rows wid*32 .. wid*32+31, 2 issues of 16 rows
    int srow_in = lane >> 2;           // 0..15
    int schunk = lane & 3;             // physical chunk this lane's 16B lands at

    // fragment read offsets (ushort units), swizzled
    int arow = wm * 64 + (lane & 31);
    int aoff0 = arow * 32 + ((((lane >> 5) ^ (arow & 3))) << 3);
    int brow = wn * 64 + (lane & 31);
    int boff0 = brow * 32 + ((((lane >> 5) ^ (brow & 3))) << 3);

    f32x16 acc00 = {}, acc01 = {}, acc10 = {}, acc11 = {};

    const u16* srcs[4] = {Ah, Al, Bh, Bl};
    int rbase[4] = {m0, m0, n0, n0};

    auto stage = [&](int buf, int kt) {
#pragma unroll
        for (int t = 0; t < 4; ++t) {
            const u16* G = srcs[t];
#pragma unroll
            for (int j = 0; j < 2; ++j) {
                int row = wid * 32 + j * 16 + srow_in;
                int gchunk = schunk ^ (row & 3);
                const u16* g = G + (size_t)(rbase[t] + row) * K + kt + gchunk * 8;
                u16* ldst = &smem[buf][t][(wid * 32 + j * 16) * 32];
                __builtin_amdgcn_global_load_lds((const __attribute__((address_space(1))) u32*)g,
                                                 (__attribute__((address_space(3))) u32*)ldst, 16, 0, 0);
            }
        }
    };

    auto compute = [&](int buf) {
        const u16* Sah = smem[buf][0];
        const u16* Sal = smem[buf][1];
        const u16* Sbh = smem[buf][2];
        const u16* Sbl = smem[buf][3];
#pragma unroll
        for (int h = 0; h < 2; ++h) {
            int x = h << 4;
            bf16x8 ah0 = *(const bf16x8*)(Sah + (aoff0 ^ x));
            bf16x8 ah1 = *(const bf16x8*)(Sah + ((aoff0 + 1024) ^ x));
            bf16x8 al0 = *(const bf16x8*)(Sal + (aoff0 ^ x));
            bf16x8 al1 = *(const bf16x8*)(Sal + ((aoff0 + 1024) ^ x));
            bf16x8 bh0 = *(const bf16x8*)(Sbh + (boff0 ^ x));
            bf16x8 bh1 = *(const bf16x8*)(Sbh + ((boff0 + 1024) ^ x));
            bf16x8 bl0 = *(const bf16x8*)(Sbl + (boff0 ^ x));
            bf16x8 bl1 = *(const bf16x8*)(Sbl + ((boff0 + 1024) ^ x));
            acc00 = __builtin_amdgcn_mfma_f32_32x32x16_bf16(ah0, bh0, acc00, 0, 0, 0);
            acc00 = __builtin_amdgcn_mfma_f32_32x32x16_bf16(ah0, bl0, acc00, 0, 0, 0);
            acc00 = __builtin_amdgcn_mfma_f32_32x32x16_bf16(al0, bh0, acc00, 0, 0, 0);
            acc01 = __builtin_amdgcn_mfma_f32_32x32x16_bf16(ah0, bh1, acc01, 0, 0, 0);
            acc01 = __builtin_amdgcn_mfma_f32_32x32x16_bf16(ah0, bl1, acc01, 0, 0, 0);
            acc01 = __builtin_amdgcn_mfma_f32_32x32x16_bf16(al0, bh1, acc01, 0, 0, 0);
            acc10 = __builtin_amdgcn_mfma_f32_32x32x16_bf16(ah1, bh0, acc10, 0, 0, 0);
            acc10 = __builtin_amdgcn_mfma_f32_32x32x16_bf16(ah1, bl0, acc10, 0, 0, 0);
            acc10 = __builtin_amdgcn_mfma_f32_32x32x16_bf16(al1, bh0, acc10, 0, 0, 0);
            acc11 = __builtin_amdgcn_mfma_f32_32x32x16_bf16(ah1, bh1, acc11, 0, 0, 0);
            acc11 = __builtin_amdgcn_mfma_f32_32x32x16_bf16(ah1, bl1, acc11, 0, 0, 0);
            acc11 = __builtin_amdgcn_mfma_f32_32x32x16_bf16(al1, bh1, acc11, 0, 0, 0);
        }
    };

    int nk = K >> 5;
    int cur = 0;
    stage(0, 0);
    __syncthreads();
    for (int t = 0; t < nk - 1; ++t) {
        stage(cur ^ 1, (t + 1) << 5);
        compute(cur);
        __syncthreads();               // drains vmcnt for stage + readers done
        cur ^= 1;
    }
    compute(cur);

    auto epi = [&](f32x16 a, int fm, int fn) {
        int col = n0 + wn * 64 + fn * 32 + (lane & 31);
        int rb = m0 + wm * 64 + fm * 32 + ((lane >> 5) << 2);
#pragma unroll
        for (int r = 0; r < 16; ++r) {
            int row = rb + (r & 3) + ((r >> 2) << 3);
            float v = a[r];
            size_t o = (size_t)row * N + col;
            if (MODE == 0) C[o] = v;
            else if (MODE == 1) C[o] = v + bias[col] + auxf[(size_t)(row & 1023) * N + col];
            else if (MODE == 2) C[o] = res[o] + (bf2f(auxh[o]) + bf2f(auxl[o])) + v + bias[col];
            else if (MODE == 3) {
                v += bias[col];
                v = 0.5f * v * (1.0f + erff(v * 0.70710678118654752f));
                split2(v, Ch[o], Cl[o]);
            }
            else if (MODE == 4) C[o] = res[o] + v + bias[col];
            else if (MODE == 5) {
                v += bias[col];
                v = fmaxf(v, 0.0f);
                split2(v, Ch[o], Cl[o]);
            }
            else if (MODE == 6) C[o] = v + bias[col];
        }
    };
    epi(acc00, 0, 0); epi(acc01, 0, 1); epi(acc10, 1, 0); epi(acc11, 1, 1);
}

// ---------------- flash attention (fp32), outputs hi/lo bf16 ----------------
__global__ __launch_bounds__(256) void attn_kernel(const float* __restrict__ qkv,
                                                   const float* __restrict__ bias,
                                                   u16* __restrict__ oh, u16* __restrict__ ol) {
    __shared__ float Qs[64][68];
    __shared__ float Ks[64][68];
    __shared__ float Vs[64][68];
    int tid = threadIdx.x;
    int tx = tid & 15, ty = tid >> 4;
    int n0 = blockIdx.x * 64;
    int bh = blockIdx.y;
    int b = bh / 12, h = bh % 12;
    const size_t ROWW = 2304;
    const float* qbase = qkv + (size_t)(b * 1024) * ROWW + h * 64;
    const float* kbase = qbase + 768;
    const float* vbase = qbase + 1536;
    int lr = tid >> 4;
    int lc4 = (tid & 15) * 4;
#pragma unroll
    for (int rr = 0; rr < 4; rr++) {
        int r = lr + rr * 16;
        *(float4*)&Qs[r][lc4] = *(const float4*)(qbase + (size_t)(n0 + r) * ROWW + lc4);
    }
    float m_i[4], l_i[4], oacc[4][4] = {};
#pragma unroll
    for (int i = 0; i < 4; i++) { m_i[i] = -1e30f; l_i[i] = 0.0f; }
    __syncthreads();
    for (int t0 = 0; t0 < 1024; t0 += 64) {
        __syncthreads();
#pragma unroll
        for (int rr = 0; rr < 4; rr++) {
            int r = lr + rr * 16;
            *(float4*)&Ks[r][lc4] = *(const float4*)(kbase + (size_t)(t0 + r) * ROWW + lc4);
            *(float4*)&Vs[r][lc4] = *(const float4*)(vbase + (size_t)(t0 + r) * ROWW + lc4);
        }
        __syncthreads();
        float s[4][4] = {};
#pragma unroll 4
        for (int d = 0; d < 64; d++) {
            float a[4], kv[4];
#pragma unroll
            for (int i = 0; i < 4; i++) a[i] = Qs[i * 16 + ty][d];
#pragma unroll
            for (int j = 0; j < 4; j++) kv[j] = Ks[j * 16 + tx][d];
#pragma unroll
            for (int i = 0; i < 4; i++)
#pragma unroll
                for (int j = 0; j < 4; j++) s[i][j] += a[i] * kv[j];
        }
        float scl[4];
#pragma unroll
        for (int i = 0; i < 4; i++) {
            int row = n0 + i * 16 + ty;
            float pm = -1e30f;
#pragma unroll
            for (int j = 0; j < 4; j++) {
                s[i][j] = s[i][j] * 0.125f + bias[(size_t)row * 1024 + t0 + j * 16 + tx];
                pm = fmaxf(pm, s[i][j]);
            }
#pragma unroll
            for (int off = 1; off < 16; off <<= 1) pm = fmaxf(pm, __shfl_xor(pm, off, 64));
            float mnew = fmaxf(m_i[i], pm);
            scl[i] = __expf(m_i[i] - mnew);
            float rs = 0.0f;
#pragma unroll
            for (int j = 0; j < 4; j++) {
                float p = __expf(s[i][j] - mnew);
                s[i][j] = p;
                rs += p;
            }
#pragma unroll
            for (int off = 1; off < 16; off <<= 1) rs += __shfl_xor(rs, off, 64);
            l_i[i] = l_i[i] * scl[i] + rs;
            m_i[i] = mnew;
        }
        __syncthreads();
#pragma unroll
        for (int i = 0; i < 4; i++)
#pragma unroll
            for (int j = 0; j < 4; j++) Ks[i * 16 + ty][j * 16 + tx] = s[i][j];
        __syncthreads();
#pragma unroll
        for (int i = 0; i < 4; i++)
#pragma unroll
            for (int j = 0; j < 4; j++) oacc[i][j] *= scl[i];
#pragma unroll 4
        for (int kk = 0; kk < 64; kk++) {
            float p[4], vv[4];
#pragma unroll
            for (int i = 0; i < 4; i++) p[i] = Ks[i * 16 + ty][kk];
#pragma unroll
            for (int j = 0; j < 4; j++) vv[j] = Vs[kk][j * 16 + tx];
#pragma unroll
            for (int i = 0; i < 4; i++)
#pragma unroll
                for (int j = 0; j < 4; j++) oacc[i][j] += p[i] * vv[j];
        }
    }
#pragma unroll
    for (int i = 0; i < 4; i++) {
        int r = n0 + i * 16 + ty;
        float invl = 1.0f / l_i[i];
#pragma unroll
        for (int j = 0; j < 4; j++) {
            size_t o = (size_t)(b * 1024 + r) * 768 + h * 64 + j * 16 + tx;
            split2(oacc[i][j] * invl, oh[o], ol[o]);
        }
    }
}

// ---------------- fold + attention gate -> out(2,3,512,512) ----------------
__global__ __launch_bounds__(256) void fold_gate(const float* __restrict__ hbuf,
                                                 const float* __restrict__ xin,
                                                 const float* __restrict__ wg,
                                                 const float* __restrict__ bngw,
                                                 const float* __restrict__ bngb,
                                                 const float* __restrict__ wx,
                                                 const float* __restrict__ bnxw,
                                                 const float* __restrict__ bnxb,
                                                 const float* __restrict__ psiw,
                                                 const float* __restrict__ psib,
                                                 float* __restrict__ out) {
    int idx = blockIdx.x * 256 + threadIdx.x;      // < 2*512*512
    int b = idx >> 18;
    int rem = idx & 262143;
    int hh = rem >> 9, ww = rem & 511;
    int n = ((hh >> 4) << 5) + (ww >> 4);
    int pr = hh & 15, pc = ww & 15;
    const float* hrow = hbuf + (size_t)(b * 1024 + n) * 768 + pr * 16 + pc;
    float g0 = hrow[0], g1 = hrow[256], g2 = hrow[512];
    size_t xoff = ((size_t)(b * 3) * 512 + hh) * 512 + ww;
    float x0 = xin[xoff], x1 = xin[xoff + 262144], x2 = xin[xoff + 524288];
    float inv = rsqrtf(1.0f + 1e-5f);
    float gg = (g0 * wg[0] + g1 * wg[1] + g2 * wg[2]) * inv * bngw[0] + bngb[0];
    float xx = (x0 * wx[0] + x1 * wx[1] + x2 * wx[2]) * inv * bnxw[0] + bnxb[0];
    float z = gg + xx;
    z = z > 0.0f ? z : 0.0f;
    float psi = 1.0f / (1.0f + expf(-(z * psiw[0] + psib[0])));
    out[xoff]          = g0 * x0 * psi;
    out[xoff + 262144] = g1 * x1 * psi;
    out[xoff + 524288] = g2 * x2 * psi;
}

// ---------------- launch ----------------
extern "C" void kernel_launch(void* const* d_in, const int* in_sizes, int n_in,
                              void* d_out, int out_size, void* d_ws, size_t ws_size,
                              hipStream_t stream) {
    (void)in_sizes; (void)n_in; (void)out_size; (void)ws_size;
    const float* x       = (const float*)d_in[0];
    const float* conv_w  = (const float*)d_in[1];
    const float* conv_b  = (const float*)d_in[2];
    const float* ln1_g   = (const float*)d_in[3];
    const float* ln1_b   = (const float*)d_in[4];
    const float* qkv_w   = (const float*)d_in[5];
    const float* proj_w  = (const float*)d_in[6];
    const float* proj_b  = (const float*)d_in[7];
    const float* attn_bs = (const float*)d_in[8];
    const float* ln2_g   = (const float*)d_in[9];
    const float* ln2_b   = (const float*)d_in[10];
    const float* mlp_w1  = (const float*)d_in[11];
    const float* mlp_b1  = (const float*)d_in[12];
    const float* mlp_w2  = (const float*)d_in[13];
    const float* mlp_b2  = (const float*)d_in[14];
    const float* op_w1   = (const float*)d_in[15];
    const float* op_b1   = (const float*)d_in[16];
    const float* op_w2   = (const float*)d_in[17];
    const float* op_b2   = (const float*)d_in[18];
    const float* ag_wg   = (const float*)d_in[19];
    const float* ag_bngw = (const float*)d_in[20];
    const float* ag_bngb = (const float*)d_in[21];
    const float* ag_wx   = (const float*)d_in[22];
    const float* ag_bnxw = (const float*)d_in[23];
    const float* ag_bnxb = (const float*)d_in[24];
    const float* ag_psiw = (const float*)d_in[25];
    const float* ag_psib = (const float*)d_in[26];
    float* out = (float*)d_out;

    // workspace layout (bytes)
    char* w8 = (char*)d_ws;
    float* t   = (float*)(w8);                        // 6,291,456 B
    u16* yh    = (u16*)(w8 + 6291456);                // 3,145,728
    u16* yl    = (u16*)(w8 + 9437184);
    u16* ath   = (u16*)(w8 + 12582912);
    u16* atl   = (u16*)(w8 + 15728640);
    u16* mh    = (u16*)(w8 + 18874368);               // 6,291,456
    u16* ml    = (u16*)(w8 + 25165824);
    float* qkv = (float*)(w8 + 31457280);             // 18,874,368
    u16* wh    = (u16*)(w8 + 50331648);               // 9,437,184
    u16* wl    = (u16*)(w8 + 59768832);               // ends 69,206,016
    float* pe  = qkv;          // alias (used only before first qkv write)
    u16* xph = mh; u16* xpl = ml;       // alias (consumed before mlp1)
    float* oph2 = qkv;                   // alias (after layers)
    u16* o1h = ath; u16* o1l = atl;      // alias (after layers)

    const size_t W_QKV = 0, W_PROJ = 1769472, W_MLP1 = 2359296, W_MLP2 = 3538944;

    pe_kernel<<<3072, 256, 0, stream>>>(pe);
    gather_kernel<<<6144, 256, 0, stream>>>(x, xph, xpl);
    fsplit<<<576, 256, 0, stream>>>(conv_w, wh, wl, 147456);
    gemm_sp<1><<<dim3(6, 16), 256, 0, stream>>>(xph, xpl, wh, wl, conv_b, nullptr, pe,
                                                nullptr, nullptr, t, nullptr, nullptr, 2048, 768, 768);

    for (int l = 0; l < 8; ++l) {
        wsplit_layer<<<4608, 256, 0, stream>>>(qkv_w + (size_t)l * 1769472, proj_w + (size_t)l * 589824,
                                               mlp_w1 + (size_t)l * 1179648, mlp_w2 + (size_t)l * 1179648,
                                               wh, wl);
        ln_kernel<<<2048, 256, 0, stream>>>(t, ln1_g + l * 768, ln1_b + l * 768, yh, yl);
        gemm_sp<0><<<dim3(18, 16), 256, 0, stream>>>(yh, yl, wh + W_QKV, wl + W_QKV, nullptr, nullptr,
                                                     nullptr, nullptr, nullptr, qkv, nullptr, nullptr,
                                                     2048, 2304, 768);
        attn_kernel<<<dim3(16, 24), 256, 0, stream>>>(qkv, attn_bs + (size_t)l * 1048576, ath, atl);
        gemm_sp<2><<<dim3(6, 16), 256, 0, stream>>>(ath, atl, wh + W_PROJ, wl + W_PROJ, proj_b + l * 768,
                                                    t, nullptr, yh, yl, t, nullptr, nullptr, 2048, 768, 768);
        ln_kernel<<<2048, 256, 0, stream>>>(t, ln2_g + l * 768, ln2_b + l * 768, yh, yl);
        gemm_sp<3><<<dim3(12, 16), 256, 0, stream>>>(yh, yl, wh + W_MLP1, wl + W_MLP1, mlp_b1 + l * 1536,
                                                     nullptr, nullptr, nullptr, nullptr, nullptr, mh, ml,
                                                     2048, 1536, 768);
        gemm_sp<4><<<dim3(6, 16), 256, 0, stream>>>(mh, ml, wh + W_MLP2, wl + W_MLP2, mlp_b2 + l * 768,
                                                    t, nullptr, nullptr, nullptr, t, nullptr, nullptr,
                                                    2048, 768, 1536);
    }

    // output head
    fsplit<<<1536, 256, 0, stream>>>(t, yh, yl, 393216);
    fsplit<<<96, 256, 0, stream>>>(op_w1, wh, wl, 24576);
    fsplit<<<96, 256, 0, stream>>>(op_w2, wh + 131072, wl + 131072, 24576);
    gemm_sp<5><<<dim3(1, 16), 256, 0, stream>>>(yh, yl, wh, wl, op_b1, nullptr, nullptr,
                                                nullptr, nullptr, nullptr, o1h, o1l, 2048, 128, 768);
    gemm_sp<6><<<dim3(6, 16), 256, 0, stream>>>(o1h, o1l, wh + 131072, wl + 131072, op_b2, nullptr,
                                                nullptr, nullptr, nullptr, oph2, nullptr, nullptr,
                                                2048, 768, 128);
    fold_gate<<<2048, 256, 0, stream>>>(oph2, x, ag_wg, ag_bngw, ag_bngb,
                                        ag_wx, ag_bnxw, ag_bnxb, ag_psiw, ag_psib, out);
}

// Round 3
// 1821.452 us; speedup vs baseline: 3.1996x; 1.4034x over previous
//
#include <hip/hip_runtime.h>
#include <math.h>

typedef unsigned short u16;
typedef unsigned int u32;
typedef __attribute__((ext_vector_type(8))) short bf16x8;
typedef __attribute__((ext_vector_type(16))) float f32x16;
typedef __attribute__((ext_vector_type(4))) float f4v;
typedef __attribute__((ext_vector_type(4))) u32 u32x4;

#define MFMA(a, b, c) __builtin_amdgcn_mfma_f32_32x32x16_bf16(a, b, c, 0, 0, 0)

// ---------------- helpers ----------------
__device__ __forceinline__ float bf2f(u16 h) { return __uint_as_float(((u32)h) << 16); }

__device__ __forceinline__ void split2(float v, u16& h, u16& l) {
    u32 u = __float_as_uint(v);
    u32 hr = (u + 0x7FFFu + ((u >> 16) & 1u)) & 0xFFFF0000u;
    h = (u16)(hr >> 16);
    float lf = v - __uint_as_float(hr);
    u32 ul = __float_as_uint(lf);
    l = (u16)((ul + 0x7FFFu + ((ul >> 16) & 1u)) >> 16);
}

__device__ __forceinline__ u32 cvtpk(float lo, float hi) {
    u32 r;
    asm("v_cvt_pk_bf16_f32 %0, %1, %2" : "=v"(r) : "v"(lo), "v"(hi));
    return r;
}

// swap high 32 lanes of a with low 32 lanes of b (known-semantics shfl version)
__device__ __forceinline__ void swap32(u32& a, u32& b, int hi) {
    u32 ta = (u32)__shfl_xor((int)a, 32);
    u32 tb = (u32)__shfl_xor((int)b, 32);
    u32 na = hi ? tb : a;
    u32 nb = hi ? b : ta;
    a = na; b = nb;
}

// P regs v[base..base+7] (f32, S^T layout) -> A-fragment hi + exact lo residual
__device__ __forceinline__ void repack(const f32x16& v, int base, int hi, bf16x8& fh, bf16x8& fl) {
    float p0 = v[base + 0], p1 = v[base + 1], p2 = v[base + 2], p3 = v[base + 3];
    float p4 = v[base + 4], p5 = v[base + 5], p6 = v[base + 6], p7 = v[base + 7];
    u32 X0 = cvtpk(p0, p1), X1 = cvtpk(p2, p3), X4 = cvtpk(p4, p5), X5 = cvtpk(p6, p7);
    float r0 = p0 - __uint_as_float(X0 << 16);
    float r1 = p1 - __uint_as_float(X0 & 0xFFFF0000u);
    float r2 = p2 - __uint_as_float(X1 << 16);
    float r3 = p3 - __uint_as_float(X1 & 0xFFFF0000u);
    float r4 = p4 - __uint_as_float(X4 << 16);
    float r5 = p5 - __uint_as_float(X4 & 0xFFFF0000u);
    float r6 = p6 - __uint_as_float(X5 << 16);
    float r7 = p7 - __uint_as_float(X5 & 0xFFFF0000u);
    u32 L0 = cvtpk(r0, r1), L1 = cvtpk(r2, r3), L4 = cvtpk(r4, r5), L5 = cvtpk(r6, r7);
    swap32(X0, X4, hi); swap32(X1, X5, hi);
    swap32(L0, L4, hi); swap32(L1, L5, hi);
    u32x4 th = {X0, X1, X4, X5};
    u32x4 tl = {L0, L1, L4, L5};
    fh = __builtin_bit_cast(bf16x8, th);
    fl = __builtin_bit_cast(bf16x8, tl);
}

// ---------------- PE table ----------------
__global__ __launch_bounds__(256) void pe_kernel(float* __restrict__ pe) {
    int idx = blockIdx.x * 256 + threadIdx.x;      // < 1024*768
    int n = idx / 768, d = idx - n * 768;
    float v = 0.0f;
    if (d < 384) {
        int pos = (d < 192) ? (n >> 5) : (n & 31);
        int dd  = (d < 192) ? d : d - 192;
        int j2  = dd & ~1;
        float dv  = expf((float)j2 * (-9.210340371976184f / 192.0f));
        float ang = (float)pos * dv;
        v = (dd & 1) ? cosf(ang) : sinf(ang);
    }
    pe[idx] = v;
}

// ---------------- patch gather ----------------
__global__ __launch_bounds__(256) void gather_kernel(const float* __restrict__ x,
                                                     u16* __restrict__ xph,
                                                     u16* __restrict__ xpl) {
    int idx = blockIdx.x * 256 + threadIdx.x;      // < 2048*768
    int m = idx / 768, col = idx - m * 768;
    int b = m >> 10, n = m & 1023;
    int ci = col >> 8, rem = col & 255;
    int pr = rem >> 4, pc = rem & 15;
    int hh = ((n >> 5) << 4) + pr;
    int ww = ((n & 31) << 4) + pc;
    float v = x[(((size_t)(b * 3 + ci) * 512) + hh) * 512 + ww];
    split2(v, xph[idx], xpl[idx]);
}

// ---------------- fp32 -> hi/lo split ----------------
__global__ __launch_bounds__(256) void fsplit(const float* __restrict__ in,
                                              u16* __restrict__ h, u16* __restrict__ l, int n4) {
    int i = blockIdx.x * 256 + threadIdx.x;
    if (i >= n4) return;
    float4 v = ((const float4*)in)[i];
    int o = i * 4;
    split2(v.x, h[o], l[o]);
    split2(v.y, h[o + 1], l[o + 1]);
    split2(v.z, h[o + 2], l[o + 2]);
    split2(v.w, h[o + 3], l[o + 3]);
}

// ---------------- per-layer weight split ----------------
__global__ __launch_bounds__(256) void wsplit_layer(const float* __restrict__ qkvw,
                                                    const float* __restrict__ projw,
                                                    const float* __restrict__ w1,
                                                    const float* __restrict__ w2,
                                                    u16* __restrict__ wh, u16* __restrict__ wl) {
    int i4 = blockIdx.x * 256 + threadIdx.x;       // < 1179648
    if (i4 >= 1179648) return;
    size_t idx = (size_t)i4 * 4;
    const float* src; size_t off;
    if (idx < 1769472)      { src = qkvw;  off = idx; }
    else if (idx < 2359296) { src = projw; off = idx - 1769472; }
    else if (idx < 3538944) { src = w1;    off = idx - 2359296; }
    else                    { src = w2;    off = idx - 3538944; }
    float4 v = *(const float4*)(src + off);
    split2(v.x, wh[idx], wl[idx]);
    split2(v.y, wh[idx + 1], wl[idx + 1]);
    split2(v.z, wh[idx + 2], wl[idx + 2]);
    split2(v.w, wh[idx + 3], wl[idx + 3]);
}

// ---------------- LayerNorm -> hi/lo ----------------
__global__ __launch_bounds__(256) void ln_kernel(const float* __restrict__ x,
                                                 const float* __restrict__ g,
                                                 const float* __restrict__ b,
                                                 u16* __restrict__ yh, u16* __restrict__ yl) {
    int row = blockIdx.x, tid = threadIdx.x;
    const float* xr = x + (size_t)row * 768;
    float v0 = xr[tid], v1 = xr[tid + 256], v2 = xr[tid + 512];
    __shared__ float red[256];
    red[tid] = v0 + v1 + v2;
    __syncthreads();
    for (int off = 128; off > 0; off >>= 1) {
        if (tid < off) red[tid] += red[tid + off];
        __syncthreads();
    }
    float mean = red[0] * (1.0f / 768.0f);
    __syncthreads();
    float d0 = v0 - mean, d1 = v1 - mean, d2 = v2 - mean;
    red[tid] = d0 * d0 + d1 * d1 + d2 * d2;
    __syncthreads();
    for (int off = 128; off > 0; off >>= 1) {
        if (tid < off) red[tid] += red[tid + off];
        __syncthreads();
    }
    float rstd = rsqrtf(red[0] * (1.0f / 768.0f) + 1e-5f);
    size_t o = (size_t)row * 768;
    split2(d0 * rstd * g[tid]       + b[tid],       yh[o + tid],       yl[o + tid]);
    split2(d1 * rstd * g[tid + 256] + b[tid + 256], yh[o + tid + 256], yl[o + tid + 256]);
    split2(d2 * rstd * g[tid + 512] + b[tid + 512], yh[o + tid + 512], yl[o + tid + 512]);
}

// ---------------- split-bf16 MFMA GEMM ----------------
// MODE 1: C=acc+bias+pe  MODE 2: C=res+(auxh+auxl)+acc+bias  MODE 3: gelu->split
// MODE 4: C=res+acc+bias MODE 5: relu->split  MODE 6: C=acc+bias  MODE 7: split
template <int MODE>
__global__ __launch_bounds__(256, 2) void gemm_sp(const u16* __restrict__ Ah, const u16* __restrict__ Al,
                                                  const u16* __restrict__ Bh, const u16* __restrict__ Bl,
                                                  const float* __restrict__ bias,
                                                  const float* __restrict__ res,
                                                  const float* __restrict__ auxf,
                                                  const u16* __restrict__ auxh, const u16* __restrict__ auxl,
                                                  float* __restrict__ C, u16* __restrict__ Ch, u16* __restrict__ Cl,
                                                  int M, int N, int K) {
    __shared__ u16 smem[2][4][4096];   // 64 KB
    int tid = threadIdx.x;
    int wid = tid >> 6, lane = tid & 63;
    int wm = wid >> 1, wn = wid & 1;
    int m0 = blockIdx.y * 128, n0 = blockIdx.x * 128;

    int srow_in = lane >> 2;
    int schunk = lane & 3;

    int arow = wm * 64 + (lane & 31);
    int aoff0 = arow * 32 + ((((lane >> 5) ^ (arow & 3))) << 3);
    int brow = wn * 64 + (lane & 31);
    int boff0 = brow * 32 + ((((lane >> 5) ^ (brow & 3))) << 3);

    f32x16 acc00 = {}, acc01 = {}, acc10 = {}, acc11 = {};

    const u16* srcs[4] = {Ah, Al, Bh, Bl};
    int rbase[4] = {m0, m0, n0, n0};

    auto stage = [&](int buf, int kt) {
#pragma unroll
        for (int t = 0; t < 4; ++t) {
            const u16* G = srcs[t];
#pragma unroll
            for (int j = 0; j < 2; ++j) {
                int row = wid * 32 + j * 16 + srow_in;
                int gchunk = schunk ^ (row & 3);
                const u16* g = G + (size_t)(rbase[t] + row) * K + kt + gchunk * 8;
                u16* ldst = &smem[buf][t][(wid * 32 + j * 16) * 32];
                __builtin_amdgcn_global_load_lds((const __attribute__((address_space(1))) u32*)g,
                                                 (__attribute__((address_space(3))) u32*)ldst, 16, 0, 0);
            }
        }
    };

    auto compute = [&](int buf) {
        const u16* Sah = smem[buf][0];
        const u16* Sal = smem[buf][1];
        const u16* Sbh = smem[buf][2];
        const u16* Sbl = smem[buf][3];
#pragma unroll
        for (int h = 0; h < 2; ++h) {
            int x = h << 4;
            bf16x8 ah0 = *(const bf16x8*)(Sah + (aoff0 ^ x));
            bf16x8 ah1 = *(const bf16x8*)(Sah + ((aoff0 + 1024) ^ x));
            bf16x8 al0 = *(const bf16x8*)(Sal + (aoff0 ^ x));
            bf16x8 al1 = *(const bf16x8*)(Sal + ((aoff0 + 1024) ^ x));
            bf16x8 bh0 = *(const bf16x8*)(Sbh + (boff0 ^ x));
            bf16x8 bh1 = *(const bf16x8*)(Sbh + ((boff0 + 1024) ^ x));
            bf16x8 bl0 = *(const bf16x8*)(Sbl + (boff0 ^ x));
            bf16x8 bl1 = *(const bf16x8*)(Sbl + ((boff0 + 1024) ^ x));
            acc00 = MFMA(ah0, bh0, acc00);
            acc00 = MFMA(ah0, bl0, acc00);
            acc00 = MFMA(al0, bh0, acc00);
            acc01 = MFMA(ah0, bh1, acc01);
            acc01 = MFMA(ah0, bl1, acc01);
            acc01 = MFMA(al0, bh1, acc01);
            acc10 = MFMA(ah1, bh0, acc10);
            acc10 = MFMA(ah1, bl0, acc10);
            acc10 = MFMA(al1, bh0, acc10);
            acc11 = MFMA(ah1, bh1, acc11);
            acc11 = MFMA(ah1, bl1, acc11);
            acc11 = MFMA(al1, bh1, acc11);
        }
    };

    int nk = K >> 5;
    int cur = 0;
    stage(0, 0);
    __syncthreads();
    for (int t = 0; t < nk - 1; ++t) {
        stage(cur ^ 1, (t + 1) << 5);
        compute(cur);
        __syncthreads();
        cur ^= 1;
    }
    compute(cur);

    auto epi = [&](f32x16 a, int fm, int fn) {
        int col = n0 + wn * 64 + fn * 32 + (lane & 31);
        int rb = m0 + wm * 64 + fm * 32 + ((lane >> 5) << 2);
#pragma unroll
        for (int r = 0; r < 16; ++r) {
            int row = rb + (r & 3) + ((r >> 2) << 3);
            float v = a[r];
            size_t o = (size_t)row * N + col;
            if (MODE == 1) C[o] = v + bias[col] + auxf[(size_t)(row & 1023) * N + col];
            else if (MODE == 2) C[o] = res[o] + (bf2f(auxh[o]) + bf2f(auxl[o])) + v + bias[col];
            else if (MODE == 3) {
                v += bias[col];
                v = 0.5f * v * (1.0f + erff(v * 0.70710678118654752f));
                split2(v, Ch[o], Cl[o]);
            }
            else if (MODE == 4) C[o] = res[o] + v + bias[col];
            else if (MODE == 5) {
                v += bias[col];
                v = fmaxf(v, 0.0f);
                split2(v, Ch[o], Cl[o]);
            }
            else if (MODE == 6) C[o] = v + bias[col];
            else if (MODE == 7) split2(v, Ch[o], Cl[o]);
        }
    };
    epi(acc00, 0, 0); epi(acc01, 0, 1); epi(acc10, 1, 0); epi(acc11, 1, 1);
}

// ---------------- V transpose: qkv V-part -> Vt [b][h][hd][1024] ----------------
__global__ __launch_bounds__(256) void vtrans(const u16* __restrict__ qh, const u16* __restrict__ ql,
                                              u16* __restrict__ vth, u16* __restrict__ vtl) {
    __shared__ u16 tl[2][64][72];
    int tid = threadIdx.x;
    int kt = blockIdx.x, bh = blockIdx.y;
    int b = bh / 12, h = bh % 12;
#pragma unroll
    for (int j = 0; j < 2; ++j) {
        int idx = tid + j * 256;
        int r = idx >> 3, c = idx & 7;
        size_t so = (size_t)(b * 1024 + kt * 64 + r) * 2304 + 1536 + h * 64 + c * 8;
        *(bf16x8*)&tl[0][r][c * 8] = *(const bf16x8*)(qh + so);
        *(bf16x8*)&tl[1][r][c * 8] = *(const bf16x8*)(ql + so);
    }
    __syncthreads();
#pragma unroll
    for (int j = 0; j < 2; ++j) {
        int idx = tid + j * 256;
        int hd = idx >> 3, c = idx & 7;
        u16 t0[8], t1[8];
#pragma unroll
        for (int i = 0; i < 8; ++i) { t0[i] = tl[0][c * 8 + i][hd]; t1[i] = tl[1][c * 8 + i][hd]; }
        size_t d = ((size_t)(b * 12 + h) * 64 + hd) * 1024 + kt * 64 + c * 8;
        *(bf16x8*)(vth + d) = *(bf16x8*)t0;
        *(bf16x8*)(vtl + d) = *(bf16x8*)t1;
    }
}

// ---------------- MFMA flash attention ----------------
// grid (16 q-tiles, 24 bh), 256 thr = 4 waves: wave(s,p) = (q-half, K-parity)
__global__ __launch_bounds__(256, 2) void attn_mfma(const u16* __restrict__ qh, const u16* __restrict__ ql,
                                                    const u16* __restrict__ vth, const u16* __restrict__ vtl,
                                                    const float* __restrict__ bias,
                                                    u16* __restrict__ oh, u16* __restrict__ ol) {
    __shared__ u16 smem[2][4][4096];   // [slot][Kh,Kl,Vth,Vtl][64*64] = 64 KB
    int tid = threadIdx.x;
    int wid = tid >> 6, lane = tid & 63;
    int s = wid & 1, p = wid >> 1;
    int lq = lane & 31;
    int hi = lane >> 5;
    int bq0 = blockIdx.x * 64;
    int bh = blockIdx.y;
    int b = bh / 12, h = bh % 12;
    int gq = bq0 + s * 32 + lq;

    // Q fragments in registers
    bf16x8 qfh[4], qfl[4];
    {
        size_t qo = (size_t)(b * 1024 + gq) * 2304 + h * 64 + hi * 8;
#pragma unroll
        for (int ks = 0; ks < 4; ++ks) {
            qfh[ks] = *(const bf16x8*)(qh + qo + ks * 16);
            qfl[ks] = *(const bf16x8*)(ql + qo + ks * 16);
        }
    }

    f32x16 oa = {}, ob = {};
    float m_i = -1e30f, l_i = 0.0f;

    for (int it = 0; it < 8; ++it) {
        // stage: wave(s,p) stages slot p comps {2s,2s+1} for tile 2it+p
        {
            int kb = (2 * it + p) * 64;
#pragma unroll
            for (int j = 0; j < 2; ++j) {
                int comp = s * 2 + j;
#pragma unroll
                for (int i = 0; i < 8; ++i) {
                    int r = 8 * i + (lane >> 3);
                    int c = (lane & 7) ^ (r & 7);
                    const u16* g;
                    if (comp == 0)      g = qh  + (size_t)(b * 1024 + kb + r) * 2304 + 768 + h * 64 + c * 8;
                    else if (comp == 1) g = ql  + (size_t)(b * 1024 + kb + r) * 2304 + 768 + h * 64 + c * 8;
                    else if (comp == 2) g = vth + ((size_t)(b * 12 + h) * 64 + r) * 1024 + kb + c * 8;
                    else                g = vtl + ((size_t)(b * 12 + h) * 64 + r) * 1024 + kb + c * 8;
                    __builtin_amdgcn_global_load_lds((const __attribute__((address_space(1))) u32*)g,
                                                     (__attribute__((address_space(3))) u32*)&smem[p][comp][i * 512],
                                                     16, 0, 0);
                }
            }
        }
        __syncthreads();

        // compute tile 2it+p from slot p
        {
            int kb = (2 * it + p) * 64;
            const u16* Kh = &smem[p][0][0];
            const u16* Kl = &smem[p][1][0];
            const u16* Vh = &smem[p][2][0];
            const u16* Vl = &smem[p][3][0];
            f32x16 sa = {}, sb = {};
#pragma unroll
            for (int ks = 0; ks < 4; ++ks) {
                int off = lq * 64 + (((2 * ks + hi) ^ (lq & 7)) << 3);
                bf16x8 kha = *(const bf16x8*)(Kh + off);
                bf16x8 khb = *(const bf16x8*)(Kh + off + 2048);
                bf16x8 kla = *(const bf16x8*)(Kl + off);
                bf16x8 klb = *(const bf16x8*)(Kl + off + 2048);
                sa = MFMA(kha, qfh[ks], sa);
                sa = MFMA(kha, qfl[ks], sa);
                sa = MFMA(kla, qfh[ks], sa);
                sb = MFMA(khb, qfh[ks], sb);
                sb = MFMA(khb, qfl[ks], sb);
                sb = MFMA(klb, qfh[ks], sb);
            }
            // scale + bias
            const float* brow = bias + (size_t)gq * 1024 + kb + (hi << 2);
#pragma unroll
            for (int g = 0; g < 4; ++g) {
                f4v bv = *(const f4v*)(brow + 8 * g);
                f4v bw = *(const f4v*)(brow + 8 * g + 32);
#pragma unroll
                for (int j = 0; j < 4; ++j) {
                    sa[4 * g + j] = sa[4 * g + j] * 0.125f + bv[j];
                    sb[4 * g + j] = sb[4 * g + j] * 0.125f + bw[j];
                }
            }
            // online softmax (per-lane scalar state; lane <-> q)
            float mt = sa[0];
#pragma unroll
            for (int r = 1; r < 16; ++r) mt = fmaxf(mt, sa[r]);
#pragma unroll
            for (int r = 0; r < 16; ++r) mt = fmaxf(mt, sb[r]);
            mt = fmaxf(mt, __shfl_xor(mt, 32));
            float mnew = fmaxf(m_i, mt);
            int up = __any(mnew > m_i);
            float scl = __expf(m_i - mnew);
            m_i = mnew;
            float ls = 0.0f;
#pragma unroll
            for (int r = 0; r < 16; ++r) { sa[r] = __expf(sa[r] - mnew); ls += sa[r]; }
#pragma unroll
            for (int r = 0; r < 16; ++r) { sb[r] = __expf(sb[r] - mnew); ls += sb[r]; }
            ls += __shfl_xor(ls, 32);
            l_i = l_i * scl + ls;
            if (up) {
#pragma unroll
                for (int r = 0; r < 16; ++r) {
                    int qr = (r & 3) + 8 * (r >> 2) + 4 * hi;
                    float fr = __shfl(scl, qr);
                    oa[r] *= fr; ob[r] *= fr;
                }
            }
            // P repack + PV
#pragma unroll
            for (int ks = 0; ks < 4; ++ks) {
                bf16x8 ph, pl;
                if (ks < 2) repack(sa, (ks & 1) * 8, hi, ph, pl);
                else        repack(sb, (ks & 1) * 8, hi, ph, pl);
                int off = lq * 64 + (((2 * ks + hi) ^ (lq & 7)) << 3);
                bf16x8 vha = *(const bf16x8*)(Vh + off);
                bf16x8 vhb = *(const bf16x8*)(Vh + off + 2048);
                bf16x8 vla = *(const bf16x8*)(Vl + off);
                bf16x8 vlb = *(const bf16x8*)(Vl + off + 2048);
                oa = MFMA(ph, vha, oa);
                oa = MFMA(ph, vla, oa);
                oa = MFMA(pl, vha, oa);
                ob = MFMA(ph, vhb, ob);
                ob = MFMA(ph, vlb, ob);
                ob = MFMA(pl, vhb, ob);
            }
        }
        __syncthreads();
    }

    // ---- merge K-parity halves ----
    float* mlb = (float*)&smem[1][0][0];    // [s][p][2][32] floats
    mlb[((s * 2 + p) * 2 + 0) * 32 + lq] = m_i;
    mlb[((s * 2 + p) * 2 + 1) * 32 + lq] = l_i;
    __syncthreads();
    float mo = mlb[((s * 2 + (p ^ 1)) * 2 + 0) * 32 + lq];
    float lo_ = mlb[((s * 2 + (p ^ 1)) * 2 + 1) * 32 + lq];
    float M = fmaxf(m_i, mo);
    float ea = __expf(m_i - M), eb = __expf(mo - M);
    float L = ea * l_i + eb * lo_;
    float f = ea / L;
    float frv[16];
#pragma unroll
    for (int r = 0; r < 16; ++r) frv[r] = __shfl(f, (r & 3) + 8 * (r >> 2) + 4 * hi);
    float* ox = (float*)&smem[0][s][0];     // 32q x 64hd f32 = 8 KB
    if (p == 1) {
#pragma unroll
        for (int r = 0; r < 16; ++r) {
            int qr = (r & 3) + 8 * (r >> 2) + 4 * hi;
            ox[qr * 64 + lq] = oa[r] * frv[r];
            ox[qr * 64 + 32 + lq] = ob[r] * frv[r];
        }
    }
    __syncthreads();
    if (p == 0) {
#pragma unroll
        for (int r = 0; r < 16; ++r) {
            int qr = (r & 3) + 8 * (r >> 2) + 4 * hi;
            float va = oa[r] * frv[r] + ox[qr * 64 + lq];
            float vb = ob[r] * frv[r] + ox[qr * 64 + 32 + lq];
            size_t d = (size_t)(b * 1024 + bq0 + s * 32 + qr) * 768 + h * 64;
            split2(va, oh[d + lq], ol[d + lq]);
            split2(vb, oh[d + 32 + lq], ol[d + 32 + lq]);
        }
    }
}

// ---------------- fold + attention gate ----------------
__global__ __launch_bounds__(256) void fold_gate(const float* __restrict__ hbuf,
                                                 const float* __restrict__ xin,
                                                 const float* __restrict__ wg,
                                                 const float* __restrict__ bngw,
                                                 const float* __restrict__ bngb,
                                                 const float* __restrict__ wx,
                                                 const float* __restrict__ bnxw,
                                                 const float* __restrict__ bnxb,
                                                 const float* __restrict__ psiw,
                                                 const float* __restrict__ psib,
                                                 float* __restrict__ out) {
    int idx = blockIdx.x * 256 + threadIdx.x;      // < 2*512*512
    int b = idx >> 18;
    int rem = idx & 262143;
    int hh = rem >> 9, ww = rem & 511;
    int n = ((hh >> 4) << 5) + (ww >> 4);
    int pr = hh & 15, pc = ww & 15;
    const float* hrow = hbuf + (size_t)(b * 1024 + n) * 768 + pr * 16 + pc;
    float g0 = hrow[0], g1 = hrow[256], g2 = hrow[512];
    size_t xoff = ((size_t)(b * 3) * 512 + hh) * 512 + ww;
    float x0 = xin[xoff], x1 = xin[xoff + 262144], x2 = xin[xoff + 524288];
    float inv = rsqrtf(1.0f + 1e-5f);
    float gg = (g0 * wg[0] + g1 * wg[1] + g2 * wg[2]) * inv * bngw[0] + bngb[0];
    float xx = (x0 * wx[0] + x1 * wx[1] + x2 * wx[2]) * inv * bnxw[0] + bnxb[0];
    float z = gg + xx;
    z = z > 0.0f ? z : 0.0f;
    float psi = 1.0f / (1.0f + expf(-(z * psiw[0] + psib[0])));
    out[xoff]          = g0 * x0 * psi;
    out[xoff + 262144] = g1 * x1 * psi;
    out[xoff + 524288] = g2 * x2 * psi;
}

// ---------------- launch ----------------
extern "C" void kernel_launch(void* const* d_in, const int* in_sizes, int n_in,
                              void* d_out, int out_size, void* d_ws, size_t ws_size,
                              hipStream_t stream) {
    (void)in_sizes; (void)n_in; (void)out_size; (void)ws_size;
    const float* x       = (const float*)d_in[0];
    const float* conv_w  = (const float*)d_in[1];
    const float* conv_b  = (const float*)d_in[2];
    const float* ln1_g   = (const float*)d_in[3];
    const float* ln1_b   = (const float*)d_in[4];
    const float* qkv_w   = (const float*)d_in[5];
    const float* proj_w  = (const float*)d_in[6];
    const float* proj_b  = (const float*)d_in[7];
    const float* attn_bs = (const float*)d_in[8];
    const float* ln2_g   = (const float*)d_in[9];
    const float* ln2_b   = (const float*)d_in[10];
    const float* mlp_w1  = (const float*)d_in[11];
    const float* mlp_b1  = (const float*)d_in[12];
    const float* mlp_w2  = (const float*)d_in[13];
    const float* mlp_b2  = (const float*)d_in[14];
    const float* op_w1   = (const float*)d_in[15];
    const float* op_b1   = (const float*)d_in[16];
    const float* op_w2   = (const float*)d_in[17];
    const float* op_b2   = (const float*)d_in[18];
    const float* ag_wg   = (const float*)d_in[19];
    const float* ag_bngw = (const float*)d_in[20];
    const float* ag_bngb = (const float*)d_in[21];
    const float* ag_wx   = (const float*)d_in[22];
    const float* ag_bnxw = (const float*)d_in[23];
    const float* ag_bnxb = (const float*)d_in[24];
    const float* ag_psiw = (const float*)d_in[25];
    const float* ag_psib = (const float*)d_in[26];
    float* out = (float*)d_out;

    // workspace layout (bytes), total 69,206,016
    char* w8 = (char*)d_ws;
    float* t   = (float*)(w8);                        // 6,291,456
    u16* yh    = (u16*)(w8 + 6291456);
    u16* yl    = (u16*)(w8 + 9437184);
    u16* ath   = (u16*)(w8 + 12582912);
    u16* atl   = (u16*)(w8 + 15728640);
    u16* mh    = (u16*)(w8 + 18874368);               // 6,291,456
    u16* ml    = (u16*)(w8 + 25165824);               // 6,291,456
    u16* qh    = (u16*)(w8 + 31457280);               // 9,437,184
    u16* ql    = (u16*)(w8 + 40894464);               // 9,437,184
    u16* wh    = (u16*)(w8 + 50331648);               // 9,437,184
    u16* wl    = (u16*)(w8 + 59768832);               // ends 69,206,016
    float* pe  = (float*)qh;            // alias (pre-layer only)
    u16* xph = mh; u16* xpl = ml;       // alias (consumed by embed gemm)
    u16* vth = mh; u16* vtl = ml;       // alias (attn phase, dead before mlp1)
    float* oph2 = (float*)qh;           // alias (after layers)
    u16* o1h = ath; u16* o1l = atl;     // alias (after layers)

    const size_t W_QKV = 0, W_PROJ = 1769472, W_MLP1 = 2359296, W_MLP2 = 3538944;

    pe_kernel<<<3072, 256, 0, stream>>>(pe);
    gather_kernel<<<6144, 256, 0, stream>>>(x, xph, xpl);
    fsplit<<<576, 256, 0, stream>>>(conv_w, wh, wl, 147456);
    gemm_sp<1><<<dim3(6, 16), 256, 0, stream>>>(xph, xpl, wh, wl, conv_b, nullptr, pe,
                                                nullptr, nullptr, t, nullptr, nullptr, 2048, 768, 768);

    for (int l = 0; l < 8; ++l) {
        wsplit_layer<<<4608, 256, 0, stream>>>(qkv_w + (size_t)l * 1769472, proj_w + (size_t)l * 589824,
                                               mlp_w1 + (size_t)l * 1179648, mlp_w2 + (size_t)l * 1179648,
                                               wh, wl);
        ln_kernel<<<2048, 256, 0, stream>>>(t, ln1_g + l * 768, ln1_b + l * 768, yh, yl);
        gemm_sp<7><<<dim3(18, 16), 256, 0, stream>>>(yh, yl, wh + W_QKV, wl + W_QKV, nullptr, nullptr,
                                                     nullptr, nullptr, nullptr, nullptr, qh, ql,
                                                     2048, 2304, 768);
        vtrans<<<dim3(16, 24), 256, 0, stream>>>(qh, ql, vth, vtl);
        attn_mfma<<<dim3(16, 24), 256, 0, stream>>>(qh, ql, vth, vtl,
                                                    attn_bs + (size_t)l * 1048576, ath, atl);
        gemm_sp<2><<<dim3(6, 16), 256, 0, stream>>>(ath, atl, wh + W_PROJ, wl + W_PROJ, proj_b + l * 768,
                                                    t, nullptr, yh, yl, t, nullptr, nullptr, 2048, 768, 768);
        ln_kernel<<<2048, 256, 0, stream>>>(t, ln2_g + l * 768, ln2_b + l * 768, yh, yl);
        gemm_sp<3><<<dim3(12, 16), 256, 0, stream>>>(yh, yl, wh + W_MLP1, wl + W_MLP1, mlp_b1 + l * 1536,
                                                     nullptr, nullptr, nullptr, nullptr, nullptr, mh, ml,
                                                     2048, 1536, 768);
        gemm_sp<4><<<dim3(6, 16), 256, 0, stream>>>(mh, ml, wh + W_MLP2, wl + W_MLP2, mlp_b2 + l * 768,
                                                    t, nullptr, nullptr, nullptr, t, nullptr, nullptr,
                                                    2048, 768, 1536);
    }

    // output head
    fsplit<<<1536, 256, 0, stream>>>(t, yh, yl, 393216);
    fsplit<<<96, 256, 0, stream>>>(op_w1, wh, wl, 24576);
    fsplit<<<96, 256, 0, stream>>>(op_w2, wh + 131072, wl + 131072, 24576);
    gemm_sp<5><<<dim3(1, 16), 256, 0, stream>>>(yh, yl, wh, wl, op_b1, nullptr, nullptr,
                                                nullptr, nullptr, nullptr, o1h, o1l, 2048, 128, 768);
    gemm_sp<6><<<dim3(6, 16), 256, 0, stream>>>(o1h, o1l, wh + 131072, wl + 131072, op_b2, nullptr,
                                                nullptr, nullptr, nullptr, oph2, nullptr, nullptr,
                                                2048, 768, 128);
    fold_gate<<<2048, 256, 0, stream>>>(oph2, x, ag_wg, ag_bngw, ag_bngb,
                                        ag_wx, ag_bnxw, ag_bnxb, ag_psiw, ag_psib, out);
}